// Round 6
// baseline (129.486 us; speedup 1.0000x reference)
//
#include <hip/hip_runtime.h>
#include <hip/hip_bf16.h>
#include <cstdint>

#define NHEADS 16
#define HDIM 64
#define BB 2
#define TSEQ 2048
#define DM 1024
#define MROWS (BB*TSEQ)   // 4096

typedef unsigned short u16;
typedef unsigned int u32;
typedef __bf16 bf16x8 __attribute__((ext_vector_type(8)));
typedef float f32x4 __attribute__((ext_vector_type(4)));

#define AS1C(p) ((const __attribute__((address_space(1))) u32*)(p))
#define AS3(p)  ((__attribute__((address_space(3))) u32*)(p))

static __device__ __forceinline__ u16 f2bf(float f) {
  return __builtin_bit_cast(u16, __float2bfloat16(f));
}
static __device__ __forceinline__ float bf2f(u16 u) {
  return __bfloat162float(__builtin_bit_cast(__hip_bfloat16, u));
}
// pack two non-NaN floats to bf16 pair (round-half-up, max rel err 2^-8)
static __device__ __forceinline__ u32 pack2bf(float a, float b) {
  const u32 ua = __builtin_bit_cast(u32, a) + 0x8000u;
  const u32 ub = __builtin_bit_cast(u32, b) + 0x8000u;
  return (ua >> 16) | (ub & 0xFFFF0000u);
}
static __device__ __forceinline__ f32x4 mfma16x16(bf16x8 a, bf16x8 b, f32x4 c) {
  return __builtin_amdgcn_mfma_f32_16x16x32_bf16(a, b, c, 0, 0, 0);
}

// ---------------- fused cast fp32 -> bf16 for x, W_qkv, W_o ----------------
#define N4_X   (MROWS * DM / 4)          // 1048576
#define N4_WQ  (3 * DM * DM / 4)         // 786432
#define N4_WO  (DM * DM / 4)             // 262144
__global__ __launch_bounds__(256) void cast_all(const float* __restrict__ x,
                                                const float* __restrict__ wq,
                                                const float* __restrict__ wo,
                                                u16* __restrict__ xb,
                                                u16* __restrict__ wqb,
                                                u16* __restrict__ wob) {
  int i = blockIdx.x * 256 + threadIdx.x;
  const int stride = gridDim.x * 256;
  for (; i < N4_X + N4_WQ + N4_WO; i += stride) {
    const float4* src; u16* dst; int j;
    if (i < N4_X)            { src = (const float4*)x;  dst = xb;  j = i; }
    else if (i < N4_X + N4_WQ) { src = (const float4*)wq; dst = wqb; j = i - N4_X; }
    else                     { src = (const float4*)wo; dst = wob; j = i - N4_X - N4_WQ; }
    float4 v = src[j];
    ushort4 o;
    o.x = f2bf(v.x); o.y = f2bf(v.y); o.z = f2bf(v.z); o.w = f2bf(v.w);
    ((ushort4*)dst)[j] = o;
  }
}

// ---------------- bf16 GEMM, C[m,n] = sum_k A[m,k]*B[n,k] ----------------
template<int WRITE_BF16>
__global__ __launch_bounds__(256, 2) void gemm_bt(const u16* __restrict__ A,
                                                  const u16* __restrict__ Bm,
                                                  float* __restrict__ Cf,
                                                  u16* __restrict__ Cb,
                                                  int M, int N, int K) {
  __shared__ u16 lA[2][128 * 32];
  __shared__ u16 lB[2][128 * 32];
  const int tid = threadIdx.x;
  const int w = tid >> 6, l = tid & 63;
  const int wr = w >> 1, wc = w & 1;
  int bid = blockIdx.y * gridDim.x + blockIdx.x;
  const int cpx = (gridDim.x * gridDim.y) >> 3;
  bid = (bid & 7) * cpx + (bid >> 3);
  const int bx = bid % gridDim.x, by = bid / gridDim.x;
  const int brow = by * 128, bcol = bx * 128;
  const int lr = l & 15, lg = l >> 4;

  const int srow = l >> 2;
  const int scol = (((l & 3) ^ (srow & 3)) * 8);  // pre-swizzled source k-offset

  auto stage = [&](int buf, int k0) {
#pragma unroll
    for (int is = 0; is < 2; ++is) {
      const int chunk = w * 2 + is;
      const int row = chunk * 16 + srow;
      __builtin_amdgcn_global_load_lds(AS1C(A + (size_t)(brow + row) * K + k0 + scol),
                                       AS3((char*)lA[buf] + chunk * 1024), 16, 0, 0);
      __builtin_amdgcn_global_load_lds(AS1C(Bm + (size_t)(bcol + row) * K + k0 + scol),
                                       AS3((char*)lB[buf] + chunk * 1024), 16, 0, 0);
    }
  };

  f32x4 acc[4][4] = {};
  const int nk = K >> 5;
  stage(0, 0);
  for (int kk = 0; kk < nk; ++kk) {
    const int cur = kk & 1;
    __syncthreads();
    if (kk + 1 < nk) stage(cur ^ 1, (kk + 1) << 5);
    bf16x8 af[4], bfr[4];
#pragma unroll
    for (int m = 0; m < 4; ++m) {
      const int row = wr * 64 + m * 16 + lr;
      const int sl = lg ^ (row & 3);
      af[m] = *(const bf16x8*)(&lA[cur][row * 32 + sl * 8]);
    }
#pragma unroll
    for (int n = 0; n < 4; ++n) {
      const int row = wc * 64 + n * 16 + lr;
      const int sl = lg ^ (row & 3);
      bfr[n] = *(const bf16x8*)(&lB[cur][row * 32 + sl * 8]);
    }
#pragma unroll
    for (int m = 0; m < 4; ++m)
#pragma unroll
      for (int n = 0; n < 4; ++n)
        acc[m][n] = mfma16x16(af[m], bfr[n], acc[m][n]);
  }
#pragma unroll
  for (int m = 0; m < 4; ++m)
#pragma unroll
    for (int n = 0; n < 4; ++n)
#pragma unroll
      for (int r = 0; r < 4; ++r) {
        const int row = brow + wr * 64 + m * 16 + lg * 4 + r;
        const int col = bcol + wc * 64 + n * 16 + lr;
        if constexpr (WRITE_BF16)
          Cb[(size_t)row * N + col] = f2bf(acc[m][n][r]);
        else
          Cf[(size_t)row * N + col] = acc[m][n][r];
      }
}

// ---------------- RoPE + reshape ----------------
// q is pre-scaled by (1/8)*log2(e) so attention scores arrive in the log2
// domain and the softmax exp becomes a raw v_exp_f32.
__global__ __launch_bounds__(256) void rope_reshape(const u16* __restrict__ qkvb,
                                                    u16* __restrict__ qb,
                                                    u16* __restrict__ kb,
                                                    u16* __restrict__ vbT) {
  const int bh = blockIdx.y;
  const int b = bh >> 4, h = bh & 15;
  const int t0 = blockIdx.x * 64;
  const int tid = threadIdx.x;
  const float C = -0.4152410118609203f;  // -log2(10000)/32
  const float QS = 0.125f * 1.44269504088896341f;

  for (int idx = tid; idx < 64 * 32; idx += 256) {
    const int tl = idx >> 5, p = idx & 31;
    const int t = t0 + tl;
    const size_t base = ((size_t)(b * TSEQ + t)) * 3072 + h * 64 + 2 * p;
    const float qe = bf2f(qkvb[base]), qo = bf2f(qkvb[base + 1]);
    const float ke = bf2f(qkvb[base + 1024]), ko = bf2f(qkvb[base + 1025]);
    const float inv = exp2f((float)p * C);
    const float ang = (float)t * inv;
    float sn, cs;
    sincosf(ang, &sn, &cs);
    const size_t ob = ((size_t)bh * TSEQ + t) * 64 + 2 * p;
    qb[ob]     = f2bf((qe * cs - qo * sn) * QS);
    qb[ob + 1] = f2bf((qe * sn + qo * cs) * QS);
    kb[ob]     = f2bf(ke * cs - ko * sn);
    kb[ob + 1] = f2bf(ke * sn + ko * cs);
  }

  __shared__ u16 lT[64][65];
  for (int idx = tid; idx < 64 * 64; idx += 256) {
    const int tl = idx >> 6, d = idx & 63;
    lT[tl][d] = qkvb[((size_t)(b * TSEQ + t0 + tl)) * 3072 + 2048 + h * 64 + d];
  }
  __syncthreads();
  for (int idx = tid; idx < 64 * 64; idx += 256) {
    const int d = idx >> 6, tl = idx & 63;
    vbT[((size_t)bh * 64 + d) * TSEQ + t0 + tl] = lT[tl][d];
  }
}

// ---------------- causal flash attention (32 q-rows/wave) ----------------
// LDS-pipe-bound fix: each wave handles 32 q-rows (2 sub-tiles of 16), so
// every K/V fragment read from LDS feeds 2 MFMAs -> K/V LDS traffic per unit
// work halves. Block: 128-row q-tile, 4 q-waves x 2 kv-groups (even/odd kv
// tiles). P buffer 2KB/wave reused across sub-tiles (write P0, read pf0,
// overwrite P1, read pf1, then one V pass feeds both). LDS 80KB -> 2 blk/CU.
// 512 blocks = 32 bh x 16 q-tiles; XCD swizzle (head-local L2) + biggest
// q-tiles dispatched first for dynamic load balance.
__global__ __launch_bounds__(512, 4) void attn_fwd(const u16* __restrict__ qb,
                                                   const u16* __restrict__ kb,
                                                   const u16* __restrict__ vbT,
                                                   u16* __restrict__ ob) {
  __shared__ u16 lK[2][2][64 * 64];   // [group][buf] 32KB
  __shared__ u16 lV[2][2][64 * 64];   // 32KB
  __shared__ u16 lP[8][16 * 64];      // 16KB (2KB/wave)
  const int hw = blockIdx.x;
  const int logical = (hw & 7) * 64 + (hw >> 3);
  const int bh = logical >> 4;            // 4 consecutive heads per XCD
  const int j = 15 - (logical & 15);      // big q-tiles first
  const int b = bh >> 4, h = bh & 15;
  const int tid = threadIdx.x;
  const int w = tid >> 6, l = tid & 63;
  const int g = w >> 2, wq = w & 3;       // kv-group, q-wave within group
  const int lr = l & 15, lg = l >> 4;
  const int srow8 = l >> 3;
  const int scol = ((l & 7) ^ srow8) * 8; // pre-swizzled source col (elems)
  const u16* Kb = kb + (size_t)bh * TSEQ * 64;
  const u16* Vb = vbT + (size_t)bh * 64 * TSEQ;
  u16* lPw = lP[w];

  const int q0 = j * 128;
  const int ntiles = 2 * j + 2;
  const int nit = j + 1;
  const int dtile = 2 * j + (wq >> 1);    // this wave's diagonal kv-tile
  const int qa0 = q0 + wq * 32 + lr;      // qsub0 absolute q row

  bf16x8 qf[2][2];
  {
    const u16* qp = qb + ((size_t)bh * TSEQ + q0 + wq * 32 + lr) * 64 + lg * 8;
    qf[0][0] = *(const bf16x8*)qp;
    qf[0][1] = *(const bf16x8*)(qp + 32);
    qp += 16 * 64;
    qf[1][0] = *(const bf16x8*)qp;
    qf[1][1] = *(const bf16x8*)(qp + 32);
  }

  f32x4 o0[4] = {}, o1[4] = {};
  float ls0 = 0.f, ls1 = 0.f;

  auto stage = [&](int buf, int kt) {
#pragma unroll
    for (int is = 0; is < 2; ++is) {
      const int chunk = wq * 2 + is;           // 0..7, 1KB each
      const int row = chunk * 8 + srow8;       // 0..63
      __builtin_amdgcn_global_load_lds(AS1C(Kb + (size_t)(kt * 64 + row) * 64 + scol),
                                       AS3((char*)lK[g][buf] + chunk * 1024), 16, 0, 0);
      __builtin_amdgcn_global_load_lds(AS1C(Vb + (size_t)row * TSEQ + kt * 64 + scol),
                                       AS3((char*)lV[g][buf] + chunk * 1024), 16, 0, 0);
    }
  };

  stage(0, g);
  for (int it = 0; it < nit; ++it) {
    const int cur = it & 1;
    __syncthreads();                  // staged buf[cur] visible
    const int ktn = 2 * (it + 1) + g;
    if (ktn < ntiles) stage(cur ^ 1, ktn);
    const int kt = 2 * it + g;
    if (kt <= dtile) {
      const u16* Kc = lK[g][cur];
      const u16* Vc = lV[g][cur];

      // S^T = K Q^T for both q-sub-tiles, sharing the K fragments
      f32x4 s0[4] = {}, s1[4] = {};
      __builtin_amdgcn_s_setprio(1);
#pragma unroll
      for (int n = 0; n < 4; ++n) {
        const int row = n * 16 + lr;
#pragma unroll
        for (int ks = 0; ks < 2; ++ks) {
          const int sl = (ks * 4 + lg) ^ (row & 7);
          bf16x8 kf = *(const bf16x8*)(&Kc[row * 64 + sl * 8]);
          s0[n] = mfma16x16(kf, qf[0][ks], s0[n]);
          s1[n] = mfma16x16(kf, qf[1][ks], s1[n]);
        }
      }
      __builtin_amdgcn_s_setprio(0);

      const bool diag = (kt == dtile);
      const int kvb = kt * 64;

      // qsub0: P = exp2(s), mask, pack -> lPw; read pf0
#pragma unroll
      for (int n = 0; n < 4; ++n) {
        float pv[4];
#pragma unroll
        for (int r = 0; r < 4; ++r) {
          float p = __builtin_amdgcn_exp2f(s0[n][r]);
          if (diag && (kvb + n * 16 + lg * 4 + r > qa0)) p = 0.f;
          pv[r] = p;
          ls0 += p;
        }
        const int phys = (n * 2 + (lg >> 1)) ^ (lr & 7);
        uint2 pk; pk.x = pack2bf(pv[0], pv[1]); pk.y = pack2bf(pv[2], pv[3]);
        *(uint2*)(&lPw[lr * 64 + phys * 8 + (lg & 1) * 4]) = pk;
      }
      bf16x8 pf0[2];
#pragma unroll
      for (int ks = 0; ks < 2; ++ks) {
        const int phys = (ks * 4 + lg) ^ (lr & 7);
        pf0[ks] = *(const bf16x8*)(&lPw[lr * 64 + phys * 8]);
      }

      // qsub1: reuse the same 2KB P buffer (wave-ordered DS ops)
#pragma unroll
      for (int n = 0; n < 4; ++n) {
        float pv[4];
#pragma unroll
        for (int r = 0; r < 4; ++r) {
          float p = __builtin_amdgcn_exp2f(s1[n][r]);
          if (diag && (kvb + n * 16 + lg * 4 + r > qa0 + 16)) p = 0.f;
          pv[r] = p;
          ls1 += p;
        }
        const int phys = (n * 2 + (lg >> 1)) ^ (lr & 7);
        uint2 pk; pk.x = pack2bf(pv[0], pv[1]); pk.y = pack2bf(pv[2], pv[3]);
        *(uint2*)(&lPw[lr * 64 + phys * 8 + (lg & 1) * 4]) = pk;
      }
      bf16x8 pf1[2];
#pragma unroll
      for (int ks = 0; ks < 2; ++ks) {
        const int phys = (ks * 4 + lg) ^ (lr & 7);
        pf1[ks] = *(const bf16x8*)(&lPw[lr * 64 + phys * 8]);
      }

      // O^T += V P^T for both sub-tiles, single V fragment pass
      __builtin_amdgcn_s_setprio(1);
#pragma unroll
      for (int n = 0; n < 4; ++n) {
        const int row = n * 16 + lr;
#pragma unroll
        for (int ks = 0; ks < 2; ++ks) {
          const int sl = (ks * 4 + lg) ^ (row & 7);
          bf16x8 vf = *(const bf16x8*)(&Vc[row * 64 + sl * 8]);
          o0[n] = mfma16x16(vf, pf0[ks], o0[n]);
          o1[n] = mfma16x16(vf, pf1[ks], o1[n]);
        }
      }
      __builtin_amdgcn_s_setprio(0);
    }
  }

  // full row sums (per-lane q=lr after reduce)
  ls0 += __shfl_xor(ls0, 16); ls0 += __shfl_xor(ls0, 32);
  ls1 += __shfl_xor(ls1, 16); ls1 += __shfl_xor(ls1, 32);

  // merge the two kv-groups' (O, l) through LDS
  __syncthreads();
  float* mO = (float*)&lK[0][0][0];   // [4 wq][2 qs][64 d][16 lr] f32 = 32KB
  float* mL = (float*)&lV[0][0][0];   // [4 wq][2 qs][16 lr]
  if (g == 1) {
#pragma unroll
    for (int qs = 0; qs < 2; ++qs)
#pragma unroll
      for (int n = 0; n < 4; ++n)
#pragma unroll
        for (int r = 0; r < 4; ++r) {
          const int d = n * 16 + lg * 4 + r;
          mO[((wq * 2 + qs) * 64 + d) * 16 + lr] = (qs ? o1[n][r] : o0[n][r]);
        }
    if (lg == 0) {
      mL[(wq * 2 + 0) * 16 + lr] = ls0;
      mL[(wq * 2 + 1) * 16 + lr] = ls1;
    }
  }
  __syncthreads();
  if (g == 0) {
    const float rl0 = 1.f / (ls0 + mL[(wq * 2 + 0) * 16 + lr]);
    const float rl1 = 1.f / (ls1 + mL[(wq * 2 + 1) * 16 + lr]);
#pragma unroll
    for (int qs = 0; qs < 2; ++qs) {
      const int q = q0 + wq * 32 + qs * 16 + lr;
      const float rl = qs ? rl1 : rl0;
#pragma unroll
      for (int n = 0; n < 4; ++n) {
        ushort4 ov;
#pragma unroll
        for (int r = 0; r < 4; ++r) {
          const int d = n * 16 + lg * 4 + r;
          const float o = (qs ? o1[n][r] : o0[n][r]) + mO[((wq * 2 + qs) * 64 + d) * 16 + lr];
          ((u16*)&ov)[r] = f2bf(o * rl);
        }
        *(ushort4*)(&ob[(size_t)(b * TSEQ + q) * DM + h * 64 + n * 16 + lg * 4]) = ov;
      }
    }
  }
}

// ---------------- launch ----------------
extern "C" void kernel_launch(void* const* d_in, const int* in_sizes, int n_in,
                              void* d_out, int out_size, void* d_ws, size_t ws_size,
                              hipStream_t stream) {
  const float* x    = (const float*)d_in[0];
  const float* Wqkv = (const float*)d_in[1];
  const float* Wo   = (const float*)d_in[2];
  float* out = (float*)d_out;

  char* ws = (char*)d_ws;
  u16* xb    = (u16*)ws; ws += (size_t)MROWS * DM * 2;
  u16* wqkvb = (u16*)ws; ws += (size_t)3 * DM * DM * 2;
  u16* wob   = (u16*)ws; ws += (size_t)DM * DM * 2;
  u16* qkvb  = (u16*)ws; ws += (size_t)MROWS * 3 * DM * 2;
  u16* qb    = (u16*)ws; ws += (size_t)BB * NHEADS * TSEQ * HDIM * 2;
  u16* kb    = (u16*)ws; ws += (size_t)BB * NHEADS * TSEQ * HDIM * 2;
  u16* vbT   = (u16*)ws; ws += (size_t)BB * NHEADS * TSEQ * HDIM * 2;
  u16* ob    = (u16*)ws; ws += (size_t)MROWS * DM * 2;

  cast_all<<<2048, 256, 0, stream>>>(x, Wqkv, Wo, xb, wqkvb, wob);

  gemm_bt<1><<<dim3(3 * DM / 128, MROWS / 128), 256, 0, stream>>>(
      xb, wqkvb, nullptr, qkvb, MROWS, 3 * DM, DM);

  rope_reshape<<<dim3(TSEQ / 64, BB * NHEADS), 256, 0, stream>>>(qkvb, qb, kb, vbT);

  attn_fwd<<<512, 512, 0, stream>>>(qb, kb, vbT, ob);

  gemm_bt<0><<<dim3(DM / 128, MROWS / 128), 256, 0, stream>>>(
      ob, wob, out, nullptr, MROWS, DM, DM);
}

// Round 7
// 117.378 us; speedup vs baseline: 1.1032x; 1.1032x over previous
//
#include <hip/hip_runtime.h>
#include <hip/hip_bf16.h>
#include <cstdint>

#define NHEADS 16
#define HDIM 64
#define BB 2
#define TSEQ 2048
#define DM 1024
#define MROWS (BB*TSEQ)   // 4096

typedef unsigned short u16;
typedef unsigned int u32;
typedef __bf16 bf16x8 __attribute__((ext_vector_type(8)));
typedef float f32x4 __attribute__((ext_vector_type(4)));

#define AS1C(p) ((const __attribute__((address_space(1))) u32*)(p))
#define AS3(p)  ((__attribute__((address_space(3))) u32*)(p))

static __device__ __forceinline__ u16 f2bf(float f) {
  return __builtin_bit_cast(u16, __float2bfloat16(f));
}
static __device__ __forceinline__ float bf2f(u16 u) {
  return __bfloat162float(__builtin_bit_cast(__hip_bfloat16, u));
}
// pack two non-NaN floats to bf16 pair (round-half-up, max rel err 2^-8)
static __device__ __forceinline__ u32 pack2bf(float a, float b) {
  const u32 ua = __builtin_bit_cast(u32, a) + 0x8000u;
  const u32 ub = __builtin_bit_cast(u32, b) + 0x8000u;
  return (ua >> 16) | (ub & 0xFFFF0000u);
}
static __device__ __forceinline__ f32x4 mfma16x16(bf16x8 a, bf16x8 b, f32x4 c) {
  return __builtin_amdgcn_mfma_f32_16x16x32_bf16(a, b, c, 0, 0, 0);
}

// ---------------- fused cast fp32 -> bf16 for x, W_qkv, W_o ----------------
#define N4_X   (MROWS * DM / 4)          // 1048576
#define N4_WQ  (3 * DM * DM / 4)         // 786432
#define N4_WO  (DM * DM / 4)             // 262144
__global__ __launch_bounds__(256) void cast_all(const float* __restrict__ x,
                                                const float* __restrict__ wq,
                                                const float* __restrict__ wo,
                                                u16* __restrict__ xb,
                                                u16* __restrict__ wqb,
                                                u16* __restrict__ wob) {
  int i = blockIdx.x * 256 + threadIdx.x;
  const int stride = gridDim.x * 256;
  for (; i < N4_X + N4_WQ + N4_WO; i += stride) {
    const float4* src; u16* dst; int j;
    if (i < N4_X)            { src = (const float4*)x;  dst = xb;  j = i; }
    else if (i < N4_X + N4_WQ) { src = (const float4*)wq; dst = wqb; j = i - N4_X; }
    else                     { src = (const float4*)wo; dst = wob; j = i - N4_X - N4_WQ; }
    float4 v = src[j];
    ushort4 o;
    o.x = f2bf(v.x); o.y = f2bf(v.y); o.z = f2bf(v.z); o.w = f2bf(v.w);
    ((ushort4*)dst)[j] = o;
  }
}

// ---------------- bf16 GEMM, C[m,n] = sum_k A[m,k]*B[n,k] ----------------
template<int WRITE_BF16>
__global__ __launch_bounds__(256, 2) void gemm_bt(const u16* __restrict__ A,
                                                  const u16* __restrict__ Bm,
                                                  float* __restrict__ Cf,
                                                  u16* __restrict__ Cb,
                                                  int M, int N, int K) {
  __shared__ u16 lA[2][128 * 32];
  __shared__ u16 lB[2][128 * 32];
  const int tid = threadIdx.x;
  const int w = tid >> 6, l = tid & 63;
  const int wr = w >> 1, wc = w & 1;
  int bid = blockIdx.y * gridDim.x + blockIdx.x;
  const int cpx = (gridDim.x * gridDim.y) >> 3;
  bid = (bid & 7) * cpx + (bid >> 3);
  const int bx = bid % gridDim.x, by = bid / gridDim.x;
  const int brow = by * 128, bcol = bx * 128;
  const int lr = l & 15, lg = l >> 4;

  const int srow = l >> 2;
  const int scol = (((l & 3) ^ (srow & 3)) * 8);  // pre-swizzled source k-offset

  auto stage = [&](int buf, int k0) {
#pragma unroll
    for (int is = 0; is < 2; ++is) {
      const int chunk = w * 2 + is;
      const int row = chunk * 16 + srow;
      __builtin_amdgcn_global_load_lds(AS1C(A + (size_t)(brow + row) * K + k0 + scol),
                                       AS3((char*)lA[buf] + chunk * 1024), 16, 0, 0);
      __builtin_amdgcn_global_load_lds(AS1C(Bm + (size_t)(bcol + row) * K + k0 + scol),
                                       AS3((char*)lB[buf] + chunk * 1024), 16, 0, 0);
    }
  };

  f32x4 acc[4][4] = {};
  const int nk = K >> 5;
  stage(0, 0);
  for (int kk = 0; kk < nk; ++kk) {
    const int cur = kk & 1;
    __syncthreads();
    if (kk + 1 < nk) stage(cur ^ 1, (kk + 1) << 5);
    bf16x8 af[4], bfr[4];
#pragma unroll
    for (int m = 0; m < 4; ++m) {
      const int row = wr * 64 + m * 16 + lr;
      const int sl = lg ^ (row & 3);
      af[m] = *(const bf16x8*)(&lA[cur][row * 32 + sl * 8]);
    }
#pragma unroll
    for (int n = 0; n < 4; ++n) {
      const int row = wc * 64 + n * 16 + lr;
      const int sl = lg ^ (row & 3);
      bfr[n] = *(const bf16x8*)(&lB[cur][row * 32 + sl * 8]);
    }
#pragma unroll
    for (int m = 0; m < 4; ++m)
#pragma unroll
      for (int n = 0; n < 4; ++n)
        acc[m][n] = mfma16x16(af[m], bfr[n], acc[m][n]);
  }
#pragma unroll
  for (int m = 0; m < 4; ++m)
#pragma unroll
    for (int n = 0; n < 4; ++n)
#pragma unroll
      for (int r = 0; r < 4; ++r) {
        const int row = brow + wr * 64 + m * 16 + lg * 4 + r;
        const int col = bcol + wc * 64 + n * 16 + lr;
        if constexpr (WRITE_BF16)
          Cb[(size_t)row * N + col] = f2bf(acc[m][n][r]);
        else
          Cf[(size_t)row * N + col] = acc[m][n][r];
      }
}

// ---------------- RoPE + reshape ----------------
// q is pre-scaled by (1/8)*log2(e) so attention scores arrive in the log2
// domain and the softmax exp becomes a raw v_exp_f32.
__global__ __launch_bounds__(256) void rope_reshape(const u16* __restrict__ qkvb,
                                                    u16* __restrict__ qb,
                                                    u16* __restrict__ kb,
                                                    u16* __restrict__ vbT) {
  const int bh = blockIdx.y;
  const int b = bh >> 4, h = bh & 15;
  const int t0 = blockIdx.x * 64;
  const int tid = threadIdx.x;
  const float C = -0.4152410118609203f;  // -log2(10000)/32
  const float QS = 0.125f * 1.44269504088896341f;

  for (int idx = tid; idx < 64 * 32; idx += 256) {
    const int tl = idx >> 5, p = idx & 31;
    const int t = t0 + tl;
    const size_t base = ((size_t)(b * TSEQ + t)) * 3072 + h * 64 + 2 * p;
    const float qe = bf2f(qkvb[base]), qo = bf2f(qkvb[base + 1]);
    const float ke = bf2f(qkvb[base + 1024]), ko = bf2f(qkvb[base + 1025]);
    const float inv = exp2f((float)p * C);
    const float ang = (float)t * inv;
    float sn, cs;
    sincosf(ang, &sn, &cs);
    const size_t ob = ((size_t)bh * TSEQ + t) * 64 + 2 * p;
    qb[ob]     = f2bf((qe * cs - qo * sn) * QS);
    qb[ob + 1] = f2bf((qe * sn + qo * cs) * QS);
    kb[ob]     = f2bf(ke * cs - ko * sn);
    kb[ob + 1] = f2bf(ke * sn + ko * cs);
  }

  __shared__ u16 lT[64][65];
  for (int idx = tid; idx < 64 * 64; idx += 256) {
    const int tl = idx >> 6, d = idx & 63;
    lT[tl][d] = qkvb[((size_t)(b * TSEQ + t0 + tl)) * 3072 + 2048 + h * 64 + d];
  }
  __syncthreads();
  for (int idx = tid; idx < 64 * 64; idx += 256) {
    const int d = idx >> 6, tl = idx & 63;
    vbT[((size_t)bh * 64 + d) * TSEQ + t0 + tl] = lT[tl][d];
  }
}

// ---------------- causal flash attention (32 q-rows/wave, paired tiles) ----
// Per block: q-tile PAIR {j, 15-j} of 128 rows each -> exactly 34 kv-tiles
// per block (uniform). 256 blocks = 32 bh x 8 pairs, 1 block/CU, 8 waves.
// Waves: 4 q-waves (32 rows each) x 2 kv-groups (even/odd kv tiles).
// Each K/V fragment feeds 2 q-sub-tile MFMAs (halved LDS traffic/work).
// XCD swizzle: each XCD owns 4 consecutive heads -> K/V L2-resident.
__global__ __launch_bounds__(512, 2) void attn_fwd(const u16* __restrict__ qb,
                                                   const u16* __restrict__ kb,
                                                   const u16* __restrict__ vbT,
                                                   u16* __restrict__ ob) {
  __shared__ u16 lK[2][2][64 * 64];   // [group][buf] 32KB
  __shared__ u16 lV[2][2][64 * 64];   // 32KB
  __shared__ u16 lP[8][16 * 64];      // 16KB (2KB/wave)
  const int hw = blockIdx.x;
  const int logical = (hw & 7) * 32 + (hw >> 3);  // 8 XCDs x 32 blocks
  const int bh = logical >> 3;            // 4 consecutive heads per XCD
  const int p8 = logical & 7;             // pair index: q-tiles {p8, 15-p8}
  const int b = bh >> 4, h = bh & 15;
  const int tid = threadIdx.x;
  const int w = tid >> 6, l = tid & 63;
  const int g = w >> 2, wq = w & 3;       // kv-group, q-wave within group
  const int lr = l & 15, lg = l >> 4;
  const int srow8 = l >> 3;
  const int scol = ((l & 7) ^ srow8) * 8; // pre-swizzled source col (elems)
  const u16* Kb = kb + (size_t)bh * TSEQ * 64;
  const u16* Vb = vbT + (size_t)bh * 64 * TSEQ;
  u16* lPw = lP[w];

  auto stage = [&](int buf, int kt) {
#pragma unroll
    for (int is = 0; is < 2; ++is) {
      const int chunk = wq * 2 + is;           // 0..7, 1KB each
      const int row = chunk * 8 + srow8;       // 0..63
      __builtin_amdgcn_global_load_lds(AS1C(Kb + (size_t)(kt * 64 + row) * 64 + scol),
                                       AS3((char*)lK[g][buf] + chunk * 1024), 16, 0, 0);
      __builtin_amdgcn_global_load_lds(AS1C(Vb + (size_t)row * TSEQ + kt * 64 + scol),
                                       AS3((char*)lV[g][buf] + chunk * 1024), 16, 0, 0);
    }
  };

  for (int half = 0; half < 2; ++half) {
    const int j = half ? (15 - p8) : p8;
    const int q0 = j * 128;
    const int ntiles = 2 * j + 2;
    const int nit = j + 1;
    const int dtile = 2 * j + (wq >> 1);  // this wave's diagonal kv-tile
    const int qa0 = q0 + wq * 32 + lr;    // qsub0 absolute q row

    bf16x8 qf[2][2];
    {
      const u16* qp = qb + ((size_t)bh * TSEQ + q0 + wq * 32 + lr) * 64 + lg * 8;
      qf[0][0] = *(const bf16x8*)qp;
      qf[0][1] = *(const bf16x8*)(qp + 32);
      qp += 16 * 64;
      qf[1][0] = *(const bf16x8*)qp;
      qf[1][1] = *(const bf16x8*)(qp + 32);
    }

    f32x4 o0[4] = {}, o1[4] = {};
    float ls0 = 0.f, ls1 = 0.f;

    __syncthreads();                  // prev half's merge reads done; LDS free
    stage(0, g);
    for (int it = 0; it < nit; ++it) {
      const int cur = it & 1;
      __syncthreads();                // staged buf[cur] visible
      const int ktn = 2 * (it + 1) + g;
      if (ktn < ntiles) stage(cur ^ 1, ktn);
      const int kt = 2 * it + g;
      if (kt <= dtile) {
        const u16* Kc = lK[g][cur];
        const u16* Vc = lV[g][cur];

        // S^T = K Q^T for both q-sub-tiles, sharing the K fragments
        f32x4 s0[4] = {}, s1[4] = {};
        __builtin_amdgcn_s_setprio(1);
#pragma unroll
        for (int n = 0; n < 4; ++n) {
          const int row = n * 16 + lr;
#pragma unroll
          for (int ks = 0; ks < 2; ++ks) {
            const int sl = (ks * 4 + lg) ^ (row & 7);
            bf16x8 kf = *(const bf16x8*)(&Kc[row * 64 + sl * 8]);
            s0[n] = mfma16x16(kf, qf[0][ks], s0[n]);
            s1[n] = mfma16x16(kf, qf[1][ks], s1[n]);
          }
        }
        __builtin_amdgcn_s_setprio(0);

        const bool diag = (kt == dtile);
        const int kvb = kt * 64;

        // qsub0: P = exp2(s), mask, pack -> lPw; read pf0
#pragma unroll
        for (int n = 0; n < 4; ++n) {
          float pv[4];
#pragma unroll
          for (int r = 0; r < 4; ++r) {
            float p = __builtin_amdgcn_exp2f(s0[n][r]);
            if (diag && (kvb + n * 16 + lg * 4 + r > qa0)) p = 0.f;
            pv[r] = p;
            ls0 += p;
          }
          const int phys = (n * 2 + (lg >> 1)) ^ (lr & 7);
          uint2 pk; pk.x = pack2bf(pv[0], pv[1]); pk.y = pack2bf(pv[2], pv[3]);
          *(uint2*)(&lPw[lr * 64 + phys * 8 + (lg & 1) * 4]) = pk;
        }
        bf16x8 pf0[2];
#pragma unroll
        for (int ks = 0; ks < 2; ++ks) {
          const int phys = (ks * 4 + lg) ^ (lr & 7);
          pf0[ks] = *(const bf16x8*)(&lPw[lr * 64 + phys * 8]);
        }

        // qsub1: reuse the same 2KB P buffer (wave-ordered DS ops)
#pragma unroll
        for (int n = 0; n < 4; ++n) {
          float pv[4];
#pragma unroll
          for (int r = 0; r < 4; ++r) {
            float p = __builtin_amdgcn_exp2f(s1[n][r]);
            if (diag && (kvb + n * 16 + lg * 4 + r > qa0 + 16)) p = 0.f;
            pv[r] = p;
            ls1 += p;
          }
          const int phys = (n * 2 + (lg >> 1)) ^ (lr & 7);
          uint2 pk; pk.x = pack2bf(pv[0], pv[1]); pk.y = pack2bf(pv[2], pv[3]);
          *(uint2*)(&lPw[lr * 64 + phys * 8 + (lg & 1) * 4]) = pk;
        }
        bf16x8 pf1[2];
#pragma unroll
        for (int ks = 0; ks < 2; ++ks) {
          const int phys = (ks * 4 + lg) ^ (lr & 7);
          pf1[ks] = *(const bf16x8*)(&lPw[lr * 64 + phys * 8]);
        }

        // O^T += V P^T for both sub-tiles, single V fragment pass
        __builtin_amdgcn_s_setprio(1);
#pragma unroll
        for (int n = 0; n < 4; ++n) {
          const int row = n * 16 + lr;
#pragma unroll
          for (int ks = 0; ks < 2; ++ks) {
            const int sl = (ks * 4 + lg) ^ (row & 7);
            bf16x8 vf = *(const bf16x8*)(&Vc[row * 64 + sl * 8]);
            o0[n] = mfma16x16(vf, pf0[ks], o0[n]);
            o1[n] = mfma16x16(vf, pf1[ks], o1[n]);
          }
        }
        __builtin_amdgcn_s_setprio(0);
      }
    }

    // full row sums (per-lane q=lr after reduce)
    ls0 += __shfl_xor(ls0, 16); ls0 += __shfl_xor(ls0, 32);
    ls1 += __shfl_xor(ls1, 16); ls1 += __shfl_xor(ls1, 32);

    // merge the two kv-groups' (O, l) through LDS
    __syncthreads();
    float* mO = (float*)&lK[0][0][0];   // [4 wq][2 qs][64 d][16 lr] f32 = 32KB
    float* mL = (float*)&lV[0][0][0];   // [4 wq][2 qs][16 lr]
    if (g == 1) {
#pragma unroll
      for (int qs = 0; qs < 2; ++qs)
#pragma unroll
        for (int n = 0; n < 4; ++n)
#pragma unroll
          for (int r = 0; r < 4; ++r) {
            const int d = n * 16 + lg * 4 + r;
            mO[((wq * 2 + qs) * 64 + d) * 16 + lr] = (qs ? o1[n][r] : o0[n][r]);
          }
      if (lg == 0) {
        mL[(wq * 2 + 0) * 16 + lr] = ls0;
        mL[(wq * 2 + 1) * 16 + lr] = ls1;
      }
    }
    __syncthreads();
    if (g == 0) {
      const float rl0 = 1.f / (ls0 + mL[(wq * 2 + 0) * 16 + lr]);
      const float rl1 = 1.f / (ls1 + mL[(wq * 2 + 1) * 16 + lr]);
#pragma unroll
      for (int qs = 0; qs < 2; ++qs) {
        const int q = q0 + wq * 32 + qs * 16 + lr;
        const float rl = qs ? rl1 : rl0;
#pragma unroll
        for (int n = 0; n < 4; ++n) {
          ushort4 ov;
#pragma unroll
          for (int r = 0; r < 4; ++r) {
            const int d = n * 16 + lg * 4 + r;
            const float o = (qs ? o1[n][r] : o0[n][r]) + mO[((wq * 2 + qs) * 64 + d) * 16 + lr];
            ((u16*)&ov)[r] = f2bf(o * rl);
          }
          *(ushort4*)(&ob[(size_t)(b * TSEQ + q) * DM + h * 64 + n * 16 + lg * 4]) = ov;
        }
      }
    }
  }
}

// ---------------- launch ----------------
extern "C" void kernel_launch(void* const* d_in, const int* in_sizes, int n_in,
                              void* d_out, int out_size, void* d_ws, size_t ws_size,
                              hipStream_t stream) {
  const float* x    = (const float*)d_in[0];
  const float* Wqkv = (const float*)d_in[1];
  const float* Wo   = (const float*)d_in[2];
  float* out = (float*)d_out;

  char* ws = (char*)d_ws;
  u16* xb    = (u16*)ws; ws += (size_t)MROWS * DM * 2;
  u16* wqkvb = (u16*)ws; ws += (size_t)3 * DM * DM * 2;
  u16* wob   = (u16*)ws; ws += (size_t)DM * DM * 2;
  u16* qkvb  = (u16*)ws; ws += (size_t)MROWS * 3 * DM * 2;
  u16* qb    = (u16*)ws; ws += (size_t)BB * NHEADS * TSEQ * HDIM * 2;
  u16* kb    = (u16*)ws; ws += (size_t)BB * NHEADS * TSEQ * HDIM * 2;
  u16* vbT   = (u16*)ws; ws += (size_t)BB * NHEADS * TSEQ * HDIM * 2;
  u16* ob    = (u16*)ws; ws += (size_t)MROWS * DM * 2;

  cast_all<<<2048, 256, 0, stream>>>(x, Wqkv, Wo, xb, wqkvb, wob);

  gemm_bt<1><<<dim3(3 * DM / 128, MROWS / 128), 256, 0, stream>>>(
      xb, wqkvb, nullptr, qkvb, MROWS, 3 * DM, DM);

  rope_reshape<<<dim3(TSEQ / 64, BB * NHEADS), 256, 0, stream>>>(qkvb, qb, kb, vbT);

  attn_fwd<<<256, 512, 0, stream>>>(qb, kb, vbT, ob);

  gemm_bt<0><<<dim3(DM / 128, MROWS / 128), 256, 0, stream>>>(
      ob, wob, out, nullptr, MROWS, DM, DM);
}